// Round 4
// baseline (189.470 us; speedup 1.0000x reference)
//
#include <hip/hip_runtime.h>

// Shapes: B=128, N=64, P=128, T=168
// x: [128,64,128] f32, x_i: [128,128] i32, g: [4096,4096] f32,
// weights: [4096,1] f32, alphas: [1,168] f32
// Out: Z [128,64] (8192 f32) then F [4096,168] (688128 f32), concat flat.
//
// Math: v = g @ w^2 (4096-vector); F = outer(v, alphas);
//       y[b,j] = sum_p alphas[xi[b,p]] * x[b,j,p]
//       Z[b,i] = sum_j v[i*64+j] * y[b,j]
//
// Round 4: SINGLE kernel node. Rowdot blocks (0..1023, 4 rows ea, wave-per-row)
// release-increment a counter when done; y-blocks (1024..1151) compute y[b,:]
// into LDS, acquire-spin until counter==1024, then compute Z[b,:] from L2-hot v.
// Counter zeroed by a 4-byte hipMemsetAsync node (graph-capturable).
// Deadlock-free for ANY occupancy/dispatch order: workers never wait.

#define GN 4096
#define TT 168
#define BB 128
#define NN 64
#define PP 128
#define NROWBLK 1024

__global__ __launch_bounds__(256) void k_all(
    const float* __restrict__ x, const int* __restrict__ xi,
    const float* __restrict__ g, const float* __restrict__ w,
    const float* __restrict__ alphas, float* __restrict__ v,
    unsigned int* __restrict__ cnt, float* __restrict__ Z,
    float* __restrict__ Fout) {
  const int t = threadIdx.x;
  if (blockIdx.x < NROWBLK) {
    // ---- row-dot: one wave per row, 4 rows per block ----
    const int wave = t >> 6, lane = t & 63;
    const int row = blockIdx.x * 4 + wave;
    const float4* g4 = (const float4*)(g + (size_t)row * GN);
    const float4* w4 = (const float4*)w;
    float s = 0.f;
    // 1024 float4 per row = 16 per lane; 8 loads in flight.
#pragma unroll 8
    for (int it = 0; it < 16; ++it) {
      float4 a = g4[it * 64 + lane];
      float4 b = w4[it * 64 + lane];
      s += a.x * (b.x * b.x) + a.y * (b.y * b.y) +
           a.z * (b.z * b.z) + a.w * (b.w * b.w);
    }
#pragma unroll
    for (int off = 32; off; off >>= 1) s += __shfl_xor(s, off, 64);
    if (lane == 0) v[row] = s;
    float* Frow = Fout + (size_t)row * TT;
    Frow[lane]      = s * alphas[lane];
    Frow[64 + lane] = s * alphas[64 + lane];
    if (lane < TT - 128) Frow[128 + lane] = s * alphas[128 + lane];
    // ---- signal completion (release, device scope) ----
    __syncthreads();                 // all waves' v/F writes issued
    if (t == 0) {
      __threadfence();               // publish block's writes device-wide
      __hip_atomic_fetch_add(cnt, 1u, __ATOMIC_RELEASE,
                             __HIP_MEMORY_SCOPE_AGENT);
    }
  } else {
    // ---- y + Z: one block per batch b; y lives in LDS only ----
    const int b = blockIdx.x - NROWBLK;
    __shared__ float ap[PP];
    __shared__ float ysh[NN];
    if (t < PP) ap[t] = alphas[xi[b * PP + t]];
    __syncthreads();
    const int j = t >> 2, r = t & 3;  // (j,r): p in [32r, 32r+32)
    const float4* xrow4 =
        (const float4*)(x + (size_t)b * (NN * PP) + (size_t)j * PP + r * 32);
    const float4* ap4 = (const float4*)(ap + r * 32);
    float s = 0.f;
#pragma unroll
    for (int k = 0; k < 8; ++k) {
      float4 a = xrow4[k];
      float4 c = ap4[k];
      s += a.x * c.x + a.y * c.y + a.z * c.z + a.w * c.w;
    }
    s += __shfl_down(s, 2, 64);
    s += __shfl_down(s, 1, 64);
    if (r == 0) ysh[j] = s;
    // ---- wait for all rowdot blocks (acquire) ----
    if (t == 0) {
      while (__hip_atomic_load(cnt, __ATOMIC_ACQUIRE,
                               __HIP_MEMORY_SCOPE_AGENT) < NROWBLK) {
        __builtin_amdgcn_s_sleep(8);
      }
      __threadfence();               // invalidate stale cached v lines
    }
    __syncthreads();                 // ysh visible + v ready for all threads
    // ---- Z[b,i] = sum_j v[i*64+j] * ysh[j]; (i, r): j in [16r, 16r+16) ----
    const int i = t >> 2;
    const float4* v4 = (const float4*)(v + i * NN + r * 16);
    const float4* y4 = (const float4*)(ysh + r * 16);
    float z = 0.f;
#pragma unroll
    for (int q = 0; q < 4; ++q) {
      float4 a = v4[q];
      float4 c = y4[q];
      z += a.x * c.x + a.y * c.y + a.z * c.z + a.w * c.w;
    }
    z += __shfl_down(z, 2, 64);
    z += __shfl_down(z, 1, 64);
    if (r == 0) Z[b * NN + i] = z;
  }
}

extern "C" void kernel_launch(void* const* d_in, const int* in_sizes, int n_in,
                              void* d_out, int out_size, void* d_ws, size_t ws_size,
                              hipStream_t stream) {
  const float* x      = (const float*)d_in[0];   // [128,64,128]
  const int*   xi     = (const int*)  d_in[1];   // [128,128]
  const float* g      = (const float*)d_in[2];   // [4096,4096]
  const float* w      = (const float*)d_in[3];   // [4096,1]
  const float* alphas = (const float*)d_in[4];   // [1,168]

  float* Z    = (float*)d_out;                   // [128,64]
  float* Fout = (float*)d_out + (BB * NN);       // [4096,168]
  float* v    = (float*)d_ws;                    // [4096]
  unsigned int* cnt = (unsigned int*)((float*)d_ws + GN);

  hipMemsetAsync(cnt, 0, sizeof(unsigned int), stream);  // graph-capturable
  k_all<<<NROWBLK + BB, 256, 0, stream>>>(x, xi, g, w, alphas, v, cnt, Z, Fout);
}

// Round 5
// 103.554 us; speedup vs baseline: 1.8297x; 1.8297x over previous
//
#include <hip/hip_runtime.h>

// Shapes: B=128, N=64, P=128, T=168
// Round 5: revert to the verified round-0 two-kernel structure (102.8 us).
// Single variable vs round 0: k_z's x-loads and v-loads vectorized to float4
// (k_z is latency-bound at 512 waves; 4x fewer VMEM instructions).
// Round-4 lesson (counters): per-block device-scope release fences = per-block
// XCD-L2 flushes -> 110 us kernel at 4% BW. Never again at this granularity.

#define GN 4096
#define TT 168
#define BB 128
#define NN 64
#define PP 128

// Kernel 1: v[row] = sum_j g[row,j] * w[j]^2 ; F[row,t] = v[row]*alphas[t]
__global__ __launch_bounds__(256) void k_rowdot(
    const float* __restrict__ g, const float* __restrict__ w,
    const float* __restrict__ alphas, float* __restrict__ v,
    float* __restrict__ Fout) {
  const int row = blockIdx.x;      // 0..4095
  const int t = threadIdx.x;       // 0..255
  const float4* g4 = (const float4*)(g + (size_t)row * GN);
  const float4* w4 = (const float4*)w;
  float s = 0.f;
#pragma unroll
  for (int it = 0; it < 4; ++it) {
    int idx = t + it * 256;        // 1024 float4 per row
    float4 a = g4[idx];
    float4 b = w4[idx];
    s += a.x * (b.x * b.x) + a.y * (b.y * b.y) + a.z * (b.z * b.z) + a.w * (b.w * b.w);
  }
  // wave (64-lane) reduction
#pragma unroll
  for (int off = 32; off > 0; off >>= 1) s += __shfl_down(s, off, 64);
  __shared__ float ls[4];
  __shared__ float vsh;
  const int wave = t >> 6, lane = t & 63;
  if (lane == 0) ls[wave] = s;
  __syncthreads();
  if (t == 0) {
    float vi = ls[0] + ls[1] + ls[2] + ls[3];
    v[row] = vi;
    vsh = vi;
  }
  __syncthreads();
  const float vi = vsh;
  if (t < TT) Fout[(size_t)row * TT + t] = vi * alphas[t];
}

// Kernel 2: per block b:
//   ap[p] = alphas[x_i[b,p]]
//   y[j]  = sum_p ap[p] * x[b,j,p]   (float4: thread (j,r) covers p in [32r,32r+32))
//   Z[b,i]= sum_j v[i*64+j] * y[j]   (float4 v loads)
__global__ __launch_bounds__(256) void k_z(
    const float* __restrict__ x, const int* __restrict__ xi,
    const float* __restrict__ alphas, const float* __restrict__ v,
    float* __restrict__ Z) {
  const int b = blockIdx.x;        // 0..127
  const int t = threadIdx.x;       // 0..255
  __shared__ float ap[PP];
  __shared__ float y[NN];
  if (t < PP) ap[t] = alphas[xi[b * PP + t]];
  __syncthreads();
  const int j = t >> 2, r = t & 3;
  const float4* xrow4 =
      (const float4*)(x + (size_t)b * (NN * PP) + (size_t)j * PP + r * 32);
  const float4* ap4 = (const float4*)(ap + r * 32);
  float s = 0.f;
#pragma unroll
  for (int k = 0; k < 8; ++k) {
    float4 a = xrow4[k];
    float4 c = ap4[k];
    s += a.x * c.x + a.y * c.y + a.z * c.z + a.w * c.w;
  }
  // reduce the quad (lanes 4j..4j+3 are within one 64-lane wave)
  s += __shfl_down(s, 2, 64);
  s += __shfl_down(s, 1, 64);
  if (r == 0) y[j] = s;
  __syncthreads();
  if (t < NN) {
    const float4* vrow4 = (const float4*)(v + t * NN);
    const float4* y4 = (const float4*)y;
    float z = 0.f;
#pragma unroll
    for (int q = 0; q < 16; ++q) {
      float4 a = vrow4[q];
      float4 c = y4[q];
      z += a.x * c.x + a.y * c.y + a.z * c.z + a.w * c.w;
    }
    Z[b * NN + t] = z;
  }
}

extern "C" void kernel_launch(void* const* d_in, const int* in_sizes, int n_in,
                              void* d_out, int out_size, void* d_ws, size_t ws_size,
                              hipStream_t stream) {
  const float* x      = (const float*)d_in[0];   // [128,64,128]
  const int*   xi     = (const int*)  d_in[1];   // [128,128]
  const float* g      = (const float*)d_in[2];   // [4096,4096]
  const float* w      = (const float*)d_in[3];   // [4096,1]
  const float* alphas = (const float*)d_in[4];   // [1,168]

  float* Z    = (float*)d_out;                   // [128,64]
  float* Fout = (float*)d_out + (BB * NN);       // [4096,168]
  float* v    = (float*)d_ws;                    // [4096] scratch

  k_rowdot<<<GN, 256, 0, stream>>>(g, w, alphas, v, Fout);
  k_z<<<BB, 256, 0, stream>>>(x, xi, alphas, v, Z);
}